// Round 6
// baseline (97.580 us; speedup 1.0000x reference)
//
#include <hip/hip_runtime.h>
#include <hip/hip_bf16.h>
#include <stdint.h>

// AttentionHead: x[8,2048,1024](f32) @ {Wq,Wk,Wv}[1024,64](f32) + bias -> flash attn -> out[8,2048,64](f32)
// f32 I/O; internal q/k/vT scratch bf16 (q pre-scaled by 1/8); f32 accumulation.
// XCD-pinned: batch b lives on XCD b (bid & 7) for both producer (k_qkv) and consumer (k_attn).

typedef __attribute__((ext_vector_type(8))) short short8;   // 8 bf16 (MFMA A/B frag)
typedef __attribute__((ext_vector_type(4))) float floatx4;  // MFMA C/D frag / 16B f32
typedef __attribute__((ext_vector_type(2))) uint32_t uint2v;
typedef __attribute__((ext_vector_type(4))) uint32_t uint4v;

static constexpr int Tn = 2048, En = 1024, Hn = 64;
static constexpr float kLog2e = 1.44269504088896340736f;

static __device__ __forceinline__ ushort f2bf(float f) {
  uint32_t u = __builtin_bit_cast(uint32_t, f);
  u += 0x7FFFu + ((u >> 16) & 1u);          // RNE
  return (ushort)(u >> 16);
}
static __device__ __forceinline__ uint32_t cvt_pk(float lo, float hi) {
  uint32_t r;
  asm("v_cvt_pk_bf16_f32 %0, %1, %2" : "=v"(r) : "v"(lo), "v"(hi));
  return r;
}

// ---------------------------------------------------------------------------
// Kernel 0: pack Wq|Wk|Wv (f32) into bf16 B-fragment order.
// wpack[kstep][ntile][lane][8]: element = W[mat][kstep*32 + (lane>>4)*8 + j][(ntile&3)*16 + (lane&15)]
__global__ __launch_bounds__(64) void k_packw(const float* __restrict__ Wq,
                                              const float* __restrict__ Wk,
                                              const float* __restrict__ Wv,
                                              ushort* __restrict__ wpack) {
  int blk = blockIdx.x;
  int kstep = blk / 12, ntile = blk % 12;
  int l = threadIdx.x;
  const float* W = (ntile < 4) ? Wq : (ntile < 8) ? Wk : Wv;
  int col = (ntile & 3) * 16 + (l & 15);
  int k0 = kstep * 32 + (l >> 4) * 8;
  short8 v;
#pragma unroll
  for (int j = 0; j < 8; ++j) v[j] = (short)f2bf(W[(k0 + j) * Hn + col]);
  *reinterpret_cast<short8*>(wpack + ((size_t)(kstep * 12 + ntile) * 64 + l) * 8) = v;
}

// ---------------------------------------------------------------------------
// Kernel 1: QKV projection. 1024 blocks x 512 thr (8 waves = 4 ns x 2 ks2).
// Wave: 3 ntiles (n0=ns*3), K-half ks2, 16 rows. Depth-2 register pipeline
// (buffers mod 3, all indices compile-time). XCD-pinned: batch = bid & 7.
__global__ __launch_bounds__(512, 4) void k_qkv(const float* __restrict__ x,
                                                const ushort* __restrict__ wpack,
                                                const float* __restrict__ bq,
                                                const float* __restrict__ bk,
                                                const float* __restrict__ bv,
                                                ushort* __restrict__ q,
                                                ushort* __restrict__ k,
                                                ushort* __restrict__ vT2) {
  __shared__ float accS[4][64][16];     // 16 KB: ks2=1 partials per ns (12 used + 4 pad)
  int l = threadIdx.x & 63;
  int w = threadIdx.x >> 6;
  int ns = w >> 1, ks2 = w & 1;
  int n0 = ns * 3;
  int batch = blockIdx.x & 7;
  int chunk = blockIdx.x >> 3;          // 0..127
  int row0 = batch * Tn + chunk * 16;
  int lq = l & 15, g = l >> 4;
  const float* xrow = x + (size_t)(row0 + lq) * En + ks2 * 512 + g * 8;
  const ushort* wp = wpack + (size_t)l * 8;

  floatx4 acc[3];
#pragma unroll
  for (int n = 0; n < 3; ++n) acc[n] = (floatx4){0.f, 0.f, 0.f, 0.f};

  floatx4 xa[3][2];
  short8 bfr[3][3];
  // prologue: prefetch i = 0, 1
#pragma unroll
  for (int i = 0; i < 2; ++i) {
    xa[i][0] = *reinterpret_cast<const floatx4*>(xrow + i * 32);
    xa[i][1] = *reinterpret_cast<const floatx4*>(xrow + i * 32 + 4);
    int ks = ks2 * 16 + i;
#pragma unroll
    for (int nn = 0; nn < 3; ++nn)
      bfr[i][nn] = *reinterpret_cast<const short8*>(wp + (size_t)(ks * 12 + n0 + nn) * 512);
  }

#pragma unroll
  for (int i = 0; i < 16; ++i) {
    const int cur = i % 3;
    if (i < 14) {                       // prefetch i+2 (two iterations ahead)
      const int pb = (i + 2) % 3;
      xa[pb][0] = *reinterpret_cast<const floatx4*>(xrow + (i + 2) * 32);
      xa[pb][1] = *reinterpret_cast<const floatx4*>(xrow + (i + 2) * 32 + 4);
      int ksn = ks2 * 16 + i + 2;
#pragma unroll
      for (int nn = 0; nn < 3; ++nn)
        bfr[pb][nn] = *reinterpret_cast<const short8*>(wp + (size_t)(ksn * 12 + n0 + nn) * 512);
    }
    uint4v aw;
    aw[0] = cvt_pk(xa[cur][0][0], xa[cur][0][1]);
    aw[1] = cvt_pk(xa[cur][0][2], xa[cur][0][3]);
    aw[2] = cvt_pk(xa[cur][1][0], xa[cur][1][1]);
    aw[3] = cvt_pk(xa[cur][1][2], xa[cur][1][3]);
    short8 af = __builtin_bit_cast(short8, aw);
#pragma unroll
    for (int nn = 0; nn < 3; ++nn)
      acc[nn] = __builtin_amdgcn_mfma_f32_16x16x32_bf16(af, bfr[cur][nn], acc[nn], 0, 0, 0);
  }

  if (ks2 == 1) {
#pragma unroll
    for (int nn = 0; nn < 3; ++nn)
      *reinterpret_cast<floatx4*>(&accS[ns][l][nn * 4]) = acc[nn];
  }
  __syncthreads();
  if (ks2 == 0) {
#pragma unroll
    for (int nn = 0; nn < 3; ++nn)
      acc[nn] += *reinterpret_cast<const floatx4*>(&accS[ns][l][nn * 4]);
#pragma unroll
    for (int nn = 0; nn < 3; ++nn) {
      int n = n0 + nn;
      int mat = n >> 2;
      int h = (n & 3) * 16 + lq;
      const float* bias = (mat == 0) ? bq : (mat == 1) ? bk : bv;
      float bias_f = bias[h];
      if (mat == 0) {          // q: pre-scale by 1/8 (softmax scale folded in)
#pragma unroll
        for (int r = 0; r < 4; ++r)
          q[(size_t)(row0 + g * 4 + r) * Hn + h] = f2bf((acc[nn][r] + bias_f) * 0.125f);
      } else if (mat == 1) {
#pragma unroll
        for (int r = 0; r < 4; ++r)
          k[(size_t)(row0 + g * 4 + r) * Hn + h] = f2bf(acc[nn][r] + bias_f);
      } else {                 // v -> vT2[b][tile][h][32]
        int tile = chunk >> 1;
        int off = (chunk & 1) * 16 + g * 4;
        uint2v pk;
        pk[0] = cvt_pk(acc[nn][0] + bias_f, acc[nn][1] + bias_f);
        pk[1] = cvt_pk(acc[nn][2] + bias_f, acc[nn][3] + bias_f);
        *reinterpret_cast<uint2v*>(vT2 + (((size_t)batch * 64 + tile) * 64 + h) * 32 + off) = pk;
      }
    }
  }
}

// ---------------------------------------------------------------------------
// Kernel 2: flash attention, VALU-lean, K AND V double-buffered (one waitcnt
// per iter for iteration-old loads). XCD-pinned: batch = bid & 7.
// 512 blocks x 512 thr: 8 waves = 2 qt x 4-way KV split, merged via LDS.
__global__ __launch_bounds__(512, 4) void k_attn(const ushort* __restrict__ qm,
                                                 const ushort* __restrict__ km,
                                                 const ushort* __restrict__ vT2,
                                                 const int* __restrict__ mask,
                                                 float* __restrict__ out) {
  __shared__ union SMem {
    ushort P[8][16 * 40];                          // in-loop per-wave P (10.2 KB)
    struct {
      float accS[2][3][64][20];                    // merge phase (33.8 KB)
      float mS[2][3][64];
      float lS[2][3][64];
    } mg;
  } sm;

  int tid = threadIdx.x;
  int l = tid & 63, w = tid >> 6;
  int qt = w >> 2, s = w & 3;
  int bid = blockIdx.x;
  int b = bid & 7;                                 // XCD-pinned batch
  int chunk = bid >> 3;                            // 0..63
  int q0 = chunk * 32 + qt * 16;
  int lq = l & 15, g = l >> 4;

  const ushort* qbase = qm + ((size_t)(b * Tn + q0 + lq)) * Hn + g * 8;
  short8 qf0 = *reinterpret_cast<const short8*>(qbase);
  short8 qf1 = *reinterpret_cast<const short8*>(qbase + 32);

  const ushort* kp = km + ((size_t)(b * Tn + s * 512) + lq) * Hn + g * 8;      // + it*2048 + t*1024 + h*32
  const ushort* vp = vT2 + (((size_t)b * 64 + s * 16) * 64 + lq) * 32 + g * 8; // + it*2048 + mt*512

  const int* mrow = mask + b * Tn + s * 512 + l;
  unsigned long long bal64[8];
#pragma unroll
  for (int j = 0; j < 8; ++j) bal64[j] = __ballot(mrow[j * 64] != 0);

  ushort* Pw = &sm.P[w][0];
  uint32_t* Pw32 = reinterpret_cast<uint32_t*>(Pw);

  float m = -1e30f, lsum = 0.f;                    // lsum is PER-LANE partial
  floatx4 acc[4];
#pragma unroll
  for (int mt = 0; mt < 4; ++mt) acc[mt] = (floatx4){0.f, 0.f, 0.f, 0.f};

  short8 kf[2][4], vfb[2][4];
#pragma unroll
  for (int t = 0; t < 2; ++t)
#pragma unroll
    for (int h = 0; h < 2; ++h)
      kf[0][t * 2 + h] = *reinterpret_cast<const short8*>(kp + t * 1024 + h * 32);
#pragma unroll
  for (int mt = 0; mt < 4; ++mt)
    vfb[0][mt] = *reinterpret_cast<const short8*>(vp + mt * 512);

#pragma unroll
  for (int it = 0; it < 16; ++it) {
    const int cur = it & 1, nxt = cur ^ 1;
    if (it < 15) {                                 // prefetch next K AND V tiles
#pragma unroll
      for (int t = 0; t < 2; ++t)
#pragma unroll
        for (int h = 0; h < 2; ++h)
          kf[nxt][t * 2 + h] =
              *reinterpret_cast<const short8*>(kp + (it + 1) * 2048 + t * 1024 + h * 32);
#pragma unroll
      for (int mt = 0; mt < 4; ++mt)
        vfb[nxt][mt] = *reinterpret_cast<const short8*>(vp + (it + 1) * 2048 + mt * 512);
    }

    // ---- QK^T (S^T): lane holds q=lq (col), kv = t*16 + g*4 + r; q pre-scaled ----
    float sc[2][4];
#pragma unroll
    for (int t = 0; t < 2; ++t) {
      floatx4 z = (floatx4){0.f, 0.f, 0.f, 0.f};
      z = __builtin_amdgcn_mfma_f32_16x16x32_bf16(kf[cur][t * 2 + 0], qf0, z, 0, 0, 0);
      z = __builtin_amdgcn_mfma_f32_16x16x32_bf16(kf[cur][t * 2 + 1], qf1, z, 0, 0, 0);
#pragma unroll
      for (int r = 0; r < 4; ++r) sc[t][r] = z[r];
    }
    // ---- mask (skipped when tile fully unmasked — wave-uniform test) ----
    unsigned int bal32 = (unsigned int)(bal64[it >> 1] >> ((it & 1) * 32));
    if (bal32 != 0xFFFFFFFFu) {
#pragma unroll
      for (int t = 0; t < 2; ++t)
#pragma unroll
        for (int r = 0; r < 4; ++r)
          if (!((bal32 >> (t * 16 + g * 4 + r)) & 1u)) sc[t][r] = -1e9f;
    }
    // ---- per-lane max; rescale only when it grows past m+8 (no shuffles) ----
    float pmax = fmaxf(fmaxf(fmaxf(sc[0][0], sc[0][1]), fmaxf(sc[0][2], sc[0][3])),
                       fmaxf(fmaxf(sc[1][0], sc[1][1]), fmaxf(sc[1][2], sc[1][3])));
    if (!__all(pmax - m <= 8.0f)) {
      float rm = fmaxf(pmax, __shfl_xor(pmax, 16));
      rm = fmaxf(rm, __shfl_xor(rm, 32));
      float mnew = fmaxf(m, rm);
      float alpha = __builtin_amdgcn_exp2f((m - mnew) * kLog2e);
      lsum *= alpha;
#pragma unroll
      for (int mt = 0; mt < 4; ++mt) acc[mt] *= alpha;
      m = mnew;
    }
    // ---- p = exp2(sc*k - m*k): 1 fma + 1 exp each ----
    float nmk = m * kLog2e;
    float p[8];
#pragma unroll
    for (int t = 0; t < 2; ++t)
#pragma unroll
      for (int r = 0; r < 4; ++r)
        p[t * 4 + r] = __builtin_amdgcn_exp2f(__builtin_fmaf(sc[t][r], kLog2e, -nmk));
    lsum += ((p[0] + p[1]) + (p[2] + p[3])) + ((p[4] + p[5]) + (p[6] + p[7]));
    // ---- pack to bf16, P round-trip through LDS (within-wave dep only) ----
    uint2v pw0, pw1;
    pw0[0] = cvt_pk(p[0], p[1]); pw0[1] = cvt_pk(p[2], p[3]);
    pw1[0] = cvt_pk(p[4], p[5]); pw1[1] = cvt_pk(p[6], p[7]);
    *reinterpret_cast<uint2v*>(Pw32 + lq * 20 + g * 2) = pw0;
    *reinterpret_cast<uint2v*>(Pw32 + lq * 20 + 8 + g * 2) = pw1;
    short8 pf = *reinterpret_cast<const short8*>(Pw + lq * 40 + g * 8);
    // ---- PV: out^T += V^T @ P^T ----
#pragma unroll
    for (int mt = 0; mt < 4; ++mt)
      acc[mt] = __builtin_amdgcn_mfma_f32_16x16x32_bf16(vfb[cur][mt], pf, acc[mt], 0, 0, 0);
  }

  // finalize per-row lsum (reduce per-lane partials over the 4 g-lanes)
  lsum += __shfl_xor(lsum, 16);
  lsum += __shfl_xor(lsum, 32);

  __syncthreads();                                 // P dead; safe to overwrite (union)
  if (s > 0) {
#pragma unroll
    for (int mt = 0; mt < 4; ++mt)
      *reinterpret_cast<floatx4*>(&sm.mg.accS[qt][s - 1][l][mt * 4]) = acc[mt];
    sm.mg.mS[qt][s - 1][l] = m;
    sm.mg.lS[qt][s - 1][l] = lsum;
  }
  __syncthreads();
  if (s == 0) {
    float mtot = m;
#pragma unroll
    for (int si = 0; si < 3; ++si) mtot = fmaxf(mtot, sm.mg.mS[qt][si][l]);
    float e0 = __builtin_amdgcn_exp2f((m - mtot) * kLog2e);
    float ltot = lsum * e0;
    float res[4][4];
#pragma unroll
    for (int mt = 0; mt < 4; ++mt)
#pragma unroll
      for (int r = 0; r < 4; ++r) res[mt][r] = acc[mt][r] * e0;
#pragma unroll
    for (int si = 0; si < 3; ++si) {
      float e = __builtin_amdgcn_exp2f((sm.mg.mS[qt][si][l] - mtot) * kLog2e);
      ltot += sm.mg.lS[qt][si][l] * e;
#pragma unroll
      for (int mt = 0; mt < 4; ++mt) {
        floatx4 a = *reinterpret_cast<const floatx4*>(&sm.mg.accS[qt][si][l][mt * 4]);
#pragma unroll
        for (int r = 0; r < 4; ++r) res[mt][r] += a[r] * e;
      }
    }
    float inv = 1.0f / ltot;
    float* obase = out + ((size_t)(b * Tn + q0 + lq)) * Hn;
#pragma unroll
    for (int mt = 0; mt < 4; ++mt) {
      floatx4 o;
#pragma unroll
      for (int r = 0; r < 4; ++r) o[r] = res[mt][r] * inv;
      *reinterpret_cast<floatx4*>(obase + mt * 16 + g * 4) = o;
    }
  }
}

// ---------------------------------------------------------------------------
extern "C" void kernel_launch(void* const* d_in, const int* in_sizes, int n_in,
                              void* d_out, int out_size, void* d_ws, size_t ws_size,
                              hipStream_t stream) {
  const float* x  = (const float*)d_in[0];
  const float* Wq = (const float*)d_in[1];
  const float* bq = (const float*)d_in[2];
  const float* Wk = (const float*)d_in[3];
  const float* bk = (const float*)d_in[4];
  const float* Wv = (const float*)d_in[5];
  const float* bv = (const float*)d_in[6];
  const int* mask = (const int*)d_in[7];
  float* outp = (float*)d_out;

  ushort* wpack = (ushort*)d_ws;                       // 384 KB
  ushort* qbuf  = wpack + 196608;                      // 2 MB bf16 (pre-scaled by 1/8)
  ushort* kbuf  = qbuf + (size_t)16384 * 64;           // 2 MB
  ushort* vT2   = kbuf + (size_t)16384 * 64;           // [8][64][64][32] bf16, 2 MB

  hipLaunchKernelGGL(k_packw, dim3(384), dim3(64), 0, stream, Wq, Wk, Wv, wpack);
  hipLaunchKernelGGL(k_qkv, dim3(1024), dim3(512), 0, stream, x, wpack, bq, bk, bv,
                     qbuf, kbuf, vT2);
  hipLaunchKernelGGL(k_attn, dim3(512), dim3(512), 0, stream, qbuf, kbuf, vT2, mask, outp);
}

// Round 9
// 85.261 us; speedup vs baseline: 1.1445x; 1.1445x over previous
//
#include <hip/hip_runtime.h>
#include <hip/hip_bf16.h>
#include <stdint.h>

// AttentionHead: x[8,2048,1024](f32) @ {Wq,Wk,Wv}[1024,64](f32) + bias -> flash attn -> out[8,2048,64](f32)
// f32 I/O; internal q/k/vT scratch bf16 (q pre-scaled by 1/8); f32 accumulation.
// XCD-pinned: batch b lives on XCD b (bid & 7) for producer and consumer.

typedef __attribute__((ext_vector_type(8))) short short8;   // 8 bf16 (MFMA A/B frag)
typedef __attribute__((ext_vector_type(4))) float floatx4;  // MFMA C/D frag / 16B f32
typedef __attribute__((ext_vector_type(2))) uint32_t uint2v;
typedef __attribute__((ext_vector_type(4))) uint32_t uint4v;

static constexpr int Tn = 2048, En = 1024, Hn = 64;
static constexpr float kLog2e = 1.44269504088896340736f;

static __device__ __forceinline__ ushort f2bf(float f) {
  uint32_t u = __builtin_bit_cast(uint32_t, f);
  u += 0x7FFFu + ((u >> 16) & 1u);          // RNE
  return (ushort)(u >> 16);
}
static __device__ __forceinline__ uint32_t cvt_pk(float lo, float hi) {
  uint32_t r;
  asm("v_cvt_pk_bf16_f32 %0, %1, %2" : "=v"(r) : "v"(lo), "v"(hi));
  return r;
}

// ---------------------------------------------------------------------------
// Kernel 0: pack Wq|Wk|Wv (f32) into bf16 B-fragment order.
__global__ __launch_bounds__(64) void k_packw(const float* __restrict__ Wq,
                                              const float* __restrict__ Wk,
                                              const float* __restrict__ Wv,
                                              ushort* __restrict__ wpack) {
  int blk = blockIdx.x;
  int kstep = blk / 12, ntile = blk % 12;
  int l = threadIdx.x;
  const float* W = (ntile < 4) ? Wq : (ntile < 8) ? Wk : Wv;
  int col = (ntile & 3) * 16 + (l & 15);
  int k0 = kstep * 32 + (l >> 4) * 8;
  short8 v;
#pragma unroll
  for (int j = 0; j < 8; ++j) v[j] = (short)f2bf(W[(k0 + j) * Hn + col]);
  *reinterpret_cast<short8*>(wpack + ((size_t)(kstep * 12 + ntile) * 64 + l) * 8) = v;
}

// ---------------------------------------------------------------------------
// Kernel 1: QKV projection — proven round-4/5 structure (mod-2 register dbuf),
// XCD-pinned. 1024 blocks x 256 thr = 4 waves (ns x ks2); 16 rows per block.
__global__ __launch_bounds__(256, 4) void k_qkv(const float* __restrict__ x,
                                                const ushort* __restrict__ wpack,
                                                const float* __restrict__ bq,
                                                const float* __restrict__ bk,
                                                const float* __restrict__ bv,
                                                ushort* __restrict__ q,
                                                ushort* __restrict__ k,
                                                ushort* __restrict__ vT2) {
  __shared__ float accS[2][64][28];
  int l = threadIdx.x & 63;
  int w = threadIdx.x >> 6;
  int ns = w & 1, ks2 = w >> 1;
  int n0 = ns * 6;
  int batch = blockIdx.x & 7;           // XCD-pinned
  int chunk = blockIdx.x >> 3;          // 0..127
  int row0 = batch * Tn + chunk * 16;
  int lq = l & 15, g = l >> 4;
  const float* xrow = x + (size_t)(row0 + lq) * En + ks2 * 512 + g * 8;
  const ushort* wp = wpack + (size_t)l * 8;

  floatx4 acc[6];
#pragma unroll
  for (int n = 0; n < 6; ++n) acc[n] = (floatx4){0.f, 0.f, 0.f, 0.f};

  floatx4 xa[2][2];
  short8 bfr[2][6];
  xa[0][0] = *reinterpret_cast<const floatx4*>(xrow);
  xa[0][1] = *reinterpret_cast<const floatx4*>(xrow + 4);
  {
    int ks = ks2 * 16;
#pragma unroll
    for (int nn = 0; nn < 6; ++nn)
      bfr[0][nn] = *reinterpret_cast<const short8*>(wp + (size_t)(ks * 12 + n0 + nn) * 512);
  }

#pragma unroll
  for (int i = 0; i < 16; ++i) {
    const int cur = i & 1, nxt = cur ^ 1;
    if (i < 15) {
      xa[nxt][0] = *reinterpret_cast<const floatx4*>(xrow + (i + 1) * 32);
      xa[nxt][1] = *reinterpret_cast<const floatx4*>(xrow + (i + 1) * 32 + 4);
      int ksn = ks2 * 16 + i + 1;
#pragma unroll
      for (int nn = 0; nn < 6; ++nn)
        bfr[nxt][nn] = *reinterpret_cast<const short8*>(wp + (size_t)(ksn * 12 + n0 + nn) * 512);
    }
    uint4v aw;
    aw[0] = cvt_pk(xa[cur][0][0], xa[cur][0][1]);
    aw[1] = cvt_pk(xa[cur][0][2], xa[cur][0][3]);
    aw[2] = cvt_pk(xa[cur][1][0], xa[cur][1][1]);
    aw[3] = cvt_pk(xa[cur][1][2], xa[cur][1][3]);
    short8 af = __builtin_bit_cast(short8, aw);
#pragma unroll
    for (int nn = 0; nn < 6; ++nn)
      acc[nn] = __builtin_amdgcn_mfma_f32_16x16x32_bf16(af, bfr[cur][nn], acc[nn], 0, 0, 0);
  }

  if (ks2 == 1) {
#pragma unroll
    for (int nn = 0; nn < 6; ++nn)
      *reinterpret_cast<floatx4*>(&accS[ns][l][nn * 4]) = acc[nn];
  }
  __syncthreads();
  if (ks2 == 0) {
#pragma unroll
    for (int nn = 0; nn < 6; ++nn)
      acc[nn] += *reinterpret_cast<const floatx4*>(&accS[ns][l][nn * 4]);
#pragma unroll
    for (int nn = 0; nn < 6; ++nn) {
      int n = n0 + nn;
      int mat = n >> 2;
      int h = (n & 3) * 16 + lq;
      const float* bias = (mat == 0) ? bq : (mat == 1) ? bk : bv;
      float bias_f = bias[h];
      if (mat == 0) {          // q: pre-scale by 1/8
#pragma unroll
        for (int r = 0; r < 4; ++r)
          q[(size_t)(row0 + g * 4 + r) * Hn + h] = f2bf((acc[nn][r] + bias_f) * 0.125f);
      } else if (mat == 1) {
#pragma unroll
        for (int r = 0; r < 4; ++r)
          k[(size_t)(row0 + g * 4 + r) * Hn + h] = f2bf(acc[nn][r] + bias_f);
      } else {                 // v -> vT2[b][tile][h][32]
        int tile = chunk >> 1;
        int off = (chunk & 1) * 16 + g * 4;
        uint2v pk;
        pk[0] = cvt_pk(acc[nn][0] + bias_f, acc[nn][1] + bias_f);
        pk[1] = cvt_pk(acc[nn][2] + bias_f, acc[nn][3] + bias_f);
        *reinterpret_cast<uint2v*>(vT2 + (((size_t)batch * 64 + tile) * 64 + h) * 32 + off) = pk;
      }
    }
  }
}

// ---------------------------------------------------------------------------
// Kernel 2: flash attention — exact round-6 passing structure (VALU-lean,
// K AND V double-buffered, XCD-pinned), plus a sched_barrier(0) pinning the
// P ds_write -> ds_read program order (alias-analysis reorder hazard, rule #18).
// 512 blocks x 512 thr: 8 waves = 2 qt x 4-way KV split, merged via LDS.
__global__ __launch_bounds__(512, 4) void k_attn(const ushort* __restrict__ qm,
                                                 const ushort* __restrict__ km,
                                                 const ushort* __restrict__ vT2,
                                                 const int* __restrict__ mask,
                                                 float* __restrict__ out) {
  __shared__ union SMem {
    ushort P[8][16 * 40];                          // in-loop per-wave P (10.2 KB)
    struct {
      float accS[2][3][64][20];                    // merge phase (33.8 KB)
      float mS[2][3][64];
      float lS[2][3][64];
    } mg;
  } sm;

  int tid = threadIdx.x;
  int l = tid & 63, w = tid >> 6;
  int qt = w >> 2, s = w & 3;
  int bid = blockIdx.x;
  int b = bid & 7;                                 // XCD-pinned batch
  int chunk = bid >> 3;                            // 0..63
  int q0 = chunk * 32 + qt * 16;
  int lq = l & 15, g = l >> 4;

  const ushort* qbase = qm + ((size_t)(b * Tn + q0 + lq)) * Hn + g * 8;
  short8 qf0 = *reinterpret_cast<const short8*>(qbase);
  short8 qf1 = *reinterpret_cast<const short8*>(qbase + 32);

  const ushort* kp = km + ((size_t)(b * Tn + s * 512) + lq) * Hn + g * 8;      // + it*2048 + t*1024 + h*32
  const ushort* vp = vT2 + (((size_t)b * 64 + s * 16) * 64 + lq) * 32 + g * 8; // + it*2048 + mt*512

  const int* mrow = mask + b * Tn + s * 512 + l;
  unsigned long long bal64[8];
#pragma unroll
  for (int j = 0; j < 8; ++j) bal64[j] = __ballot(mrow[j * 64] != 0);

  ushort* Pw = &sm.P[w][0];
  uint32_t* Pw32 = reinterpret_cast<uint32_t*>(Pw);

  float m = -1e30f, lsum = 0.f;                    // lsum is PER-LANE partial
  floatx4 acc[4];
#pragma unroll
  for (int mt = 0; mt < 4; ++mt) acc[mt] = (floatx4){0.f, 0.f, 0.f, 0.f};

  short8 kf[2][4], vfb[2][4];
#pragma unroll
  for (int t = 0; t < 2; ++t)
#pragma unroll
    for (int h = 0; h < 2; ++h)
      kf[0][t * 2 + h] = *reinterpret_cast<const short8*>(kp + t * 1024 + h * 32);
#pragma unroll
  for (int mt = 0; mt < 4; ++mt)
    vfb[0][mt] = *reinterpret_cast<const short8*>(vp + mt * 512);

#pragma unroll
  for (int it = 0; it < 16; ++it) {
    const int cur = it & 1, nxt = cur ^ 1;
    if (it < 15) {                                 // prefetch next K AND V tiles
#pragma unroll
      for (int t = 0; t < 2; ++t)
#pragma unroll
        for (int h = 0; h < 2; ++h)
          kf[nxt][t * 2 + h] =
              *reinterpret_cast<const short8*>(kp + (it + 1) * 2048 + t * 1024 + h * 32);
#pragma unroll
      for (int mt = 0; mt < 4; ++mt)
        vfb[nxt][mt] = *reinterpret_cast<const short8*>(vp + (it + 1) * 2048 + mt * 512);
    }

    // ---- QK^T (S^T): lane holds q=lq (col), kv = t*16 + g*4 + r; q pre-scaled ----
    float sc[2][4];
#pragma unroll
    for (int t = 0; t < 2; ++t) {
      floatx4 z = (floatx4){0.f, 0.f, 0.f, 0.f};
      z = __builtin_amdgcn_mfma_f32_16x16x32_bf16(kf[cur][t * 2 + 0], qf0, z, 0, 0, 0);
      z = __builtin_amdgcn_mfma_f32_16x16x32_bf16(kf[cur][t * 2 + 1], qf1, z, 0, 0, 0);
#pragma unroll
      for (int r = 0; r < 4; ++r) sc[t][r] = z[r];
    }
    // ---- mask (skipped when tile fully unmasked — wave-uniform test) ----
    unsigned int bal32 = (unsigned int)(bal64[it >> 1] >> ((it & 1) * 32));
    if (bal32 != 0xFFFFFFFFu) {
#pragma unroll
      for (int t = 0; t < 2; ++t)
#pragma unroll
        for (int r = 0; r < 4; ++r)
          if (!((bal32 >> (t * 16 + g * 4 + r)) & 1u)) sc[t][r] = -1e9f;
    }
    // ---- per-lane max; rescale only when it grows past m+8 (no shuffles) ----
    float pmax = fmaxf(fmaxf(fmaxf(sc[0][0], sc[0][1]), fmaxf(sc[0][2], sc[0][3])),
                       fmaxf(fmaxf(sc[1][0], sc[1][1]), fmaxf(sc[1][2], sc[1][3])));
    if (!__all(pmax - m <= 8.0f)) {
      float rm = fmaxf(pmax, __shfl_xor(pmax, 16));
      rm = fmaxf(rm, __shfl_xor(rm, 32));
      float mnew = fmaxf(m, rm);
      float alpha = __builtin_amdgcn_exp2f((m - mnew) * kLog2e);
      lsum *= alpha;
#pragma unroll
      for (int mt = 0; mt < 4; ++mt) acc[mt] *= alpha;
      m = mnew;
    }
    // ---- p = exp2(sc*k - m*k): 1 fma + 1 exp each ----
    float nmk = m * kLog2e;
    float p[8];
#pragma unroll
    for (int t = 0; t < 2; ++t)
#pragma unroll
      for (int r = 0; r < 4; ++r)
        p[t * 4 + r] = __builtin_amdgcn_exp2f(__builtin_fmaf(sc[t][r], kLog2e, -nmk));
    lsum += ((p[0] + p[1]) + (p[2] + p[3])) + ((p[4] + p[5]) + (p[6] + p[7]));
    // ---- pack to bf16, P round-trip through LDS (within-wave dep only) ----
    uint2v pw0, pw1;
    pw0[0] = cvt_pk(p[0], p[1]); pw0[1] = cvt_pk(p[2], p[3]);
    pw1[0] = cvt_pk(p[4], p[5]); pw1[1] = cvt_pk(p[6], p[7]);
    *reinterpret_cast<uint2v*>(Pw32 + lq * 20 + g * 2) = pw0;
    *reinterpret_cast<uint2v*>(Pw32 + lq * 20 + 8 + g * 2) = pw1;
    __builtin_amdgcn_sched_barrier(0);             // pin ds_write -> ds_read order
    short8 pf = *reinterpret_cast<const short8*>(Pw + lq * 40 + g * 8);
    // ---- PV: out^T += V^T @ P^T ----
#pragma unroll
    for (int mt = 0; mt < 4; ++mt)
      acc[mt] = __builtin_amdgcn_mfma_f32_16x16x32_bf16(vfb[cur][mt], pf, acc[mt], 0, 0, 0);
  }

  // finalize per-row lsum (reduce per-lane partials over the 4 g-lanes)
  lsum += __shfl_xor(lsum, 16);
  lsum += __shfl_xor(lsum, 32);

  __syncthreads();                                 // P dead; safe to overwrite (union)
  if (s > 0) {
#pragma unroll
    for (int mt = 0; mt < 4; ++mt)
      *reinterpret_cast<floatx4*>(&sm.mg.accS[qt][s - 1][l][mt * 4]) = acc[mt];
    sm.mg.mS[qt][s - 1][l] = m;
    sm.mg.lS[qt][s - 1][l] = lsum;
  }
  __syncthreads();
  if (s == 0) {
    float mtot = m;
#pragma unroll
    for (int si = 0; si < 3; ++si) mtot = fmaxf(mtot, sm.mg.mS[qt][si][l]);
    float e0 = __builtin_amdgcn_exp2f((m - mtot) * kLog2e);
    float ltot = lsum * e0;
    float res[4][4];
#pragma unroll
    for (int mt = 0; mt < 4; ++mt)
#pragma unroll
      for (int r = 0; r < 4; ++r) res[mt][r] = acc[mt][r] * e0;
#pragma unroll
    for (int si = 0; si < 3; ++si) {
      float e = __builtin_amdgcn_exp2f((sm.mg.mS[qt][si][l] - mtot) * kLog2e);
      ltot += sm.mg.lS[qt][si][l] * e;
#pragma unroll
      for (int mt = 0; mt < 4; ++mt) {
        floatx4 a = *reinterpret_cast<const floatx4*>(&sm.mg.accS[qt][si][l][mt * 4]);
#pragma unroll
        for (int r = 0; r < 4; ++r) res[mt][r] += a[r] * e;
      }
    }
    float inv = 1.0f / ltot;
    float* obase = out + ((size_t)(b * Tn + q0 + lq)) * Hn;
#pragma unroll
    for (int mt = 0; mt < 4; ++mt) {
      floatx4 o;
#pragma unroll
      for (int r = 0; r < 4; ++r) o[r] = res[mt][r] * inv;
      *reinterpret_cast<floatx4*>(obase + mt * 16 + g * 4) = o;
    }
  }
}

// ---------------------------------------------------------------------------
extern "C" void kernel_launch(void* const* d_in, const int* in_sizes, int n_in,
                              void* d_out, int out_size, void* d_ws, size_t ws_size,
                              hipStream_t stream) {
  const float* x  = (const float*)d_in[0];
  const float* Wq = (const float*)d_in[1];
  const float* bq = (const float*)d_in[2];
  const float* Wk = (const float*)d_in[3];
  const float* bk = (const float*)d_in[4];
  const float* Wv = (const float*)d_in[5];
  const float* bv = (const float*)d_in[6];
  const int* mask = (const int*)d_in[7];
  float* outp = (float*)d_out;

  ushort* wpack = (ushort*)d_ws;                       // 384 KB
  ushort* qbuf  = wpack + 196608;                      // 2 MB bf16 (pre-scaled by 1/8)
  ushort* kbuf  = qbuf + (size_t)16384 * 64;           // 2 MB
  ushort* vT2   = kbuf + (size_t)16384 * 64;           // [8][64][64][32] bf16, 2 MB

  hipLaunchKernelGGL(k_packw, dim3(384), dim3(64), 0, stream, Wq, Wk, Wv, wpack);
  hipLaunchKernelGGL(k_qkv, dim3(1024), dim3(256), 0, stream, x, wpack, bq, bk, bv,
                     qbuf, kbuf, vT2);
  hipLaunchKernelGGL(k_attn, dim3(512), dim3(512), 0, stream, qbuf, kbuf, vT2, mask, outp);
}

// Round 10
// 69.335 us; speedup vs baseline: 1.4074x; 1.2297x over previous
//
#include <hip/hip_runtime.h>
#include <hip/hip_bf16.h>
#include <stdint.h>

// AttentionHead: x[8,2048,1024](f32) @ {Wq,Wk,Wv}[1024,64](f32) + bias -> flash attn -> out[8,2048,64](f32)
// f32 I/O; internal q/k/vT scratch bf16 (q pre-scaled by 1/8); f32 accumulation.
// XCD-pinned: batch b lives on XCD b (bid & 7) for producer and consumer.

typedef __attribute__((ext_vector_type(8))) short short8;   // 8 bf16 (MFMA A/B frag)
typedef __attribute__((ext_vector_type(4))) float floatx4;  // MFMA C/D frag / 16B f32
typedef __attribute__((ext_vector_type(2))) uint32_t uint2v;
typedef __attribute__((ext_vector_type(4))) uint32_t uint4v;

static constexpr int Tn = 2048, En = 1024, Hn = 64;
static constexpr float kLog2e = 1.44269504088896340736f;

static __device__ __forceinline__ ushort f2bf(float f) {
  uint32_t u = __builtin_bit_cast(uint32_t, f);
  u += 0x7FFFu + ((u >> 16) & 1u);          // RNE
  return (ushort)(u >> 16);
}
static __device__ __forceinline__ uint32_t cvt_pk(float lo, float hi) {
  uint32_t r;
  asm("v_cvt_pk_bf16_f32 %0, %1, %2" : "=v"(r) : "v"(lo), "v"(hi));
  return r;
}

// ---------------------------------------------------------------------------
// Kernel 0: pack Wq|Wk|Wv (f32) into bf16 B-fragment order.
__global__ __launch_bounds__(64) void k_packw(const float* __restrict__ Wq,
                                              const float* __restrict__ Wk,
                                              const float* __restrict__ Wv,
                                              ushort* __restrict__ wpack) {
  int blk = blockIdx.x;
  int kstep = blk / 12, ntile = blk % 12;
  int l = threadIdx.x;
  const float* W = (ntile < 4) ? Wq : (ntile < 8) ? Wk : Wv;
  int col = (ntile & 3) * 16 + (l & 15);
  int k0 = kstep * 32 + (l >> 4) * 8;
  short8 v;
#pragma unroll
  for (int j = 0; j < 8; ++j) v[j] = (short)f2bf(W[(k0 + j) * Hn + col]);
  *reinterpret_cast<short8*>(wpack + ((size_t)(kstep * 12 + ntile) * 64 + l) * 8) = v;
}

// ---------------------------------------------------------------------------
// Kernel 1: QKV projection — proven structure (mod-2 register dbuf), XCD-pinned.
// 1024 blocks x 256 thr = 4 waves (ns x ks2); 16 rows per block.
__global__ __launch_bounds__(256, 4) void k_qkv(const float* __restrict__ x,
                                                const ushort* __restrict__ wpack,
                                                const float* __restrict__ bq,
                                                const float* __restrict__ bk,
                                                const float* __restrict__ bv,
                                                ushort* __restrict__ q,
                                                ushort* __restrict__ k,
                                                ushort* __restrict__ vT2) {
  __shared__ float accS[2][64][28];
  int l = threadIdx.x & 63;
  int w = threadIdx.x >> 6;
  int ns = w & 1, ks2 = w >> 1;
  int n0 = ns * 6;
  int batch = blockIdx.x & 7;           // XCD-pinned
  int chunk = blockIdx.x >> 3;          // 0..127
  int row0 = batch * Tn + chunk * 16;
  int lq = l & 15, g = l >> 4;
  const float* xrow = x + (size_t)(row0 + lq) * En + ks2 * 512 + g * 8;
  const ushort* wp = wpack + (size_t)l * 8;

  floatx4 acc[6];
#pragma unroll
  for (int n = 0; n < 6; ++n) acc[n] = (floatx4){0.f, 0.f, 0.f, 0.f};

  floatx4 xa[2][2];
  short8 bfr[2][6];
  xa[0][0] = *reinterpret_cast<const floatx4*>(xrow);
  xa[0][1] = *reinterpret_cast<const floatx4*>(xrow + 4);
  {
    int ks = ks2 * 16;
#pragma unroll
    for (int nn = 0; nn < 6; ++nn)
      bfr[0][nn] = *reinterpret_cast<const short8*>(wp + (size_t)(ks * 12 + n0 + nn) * 512);
  }

#pragma unroll
  for (int i = 0; i < 16; ++i) {
    const int cur = i & 1, nxt = cur ^ 1;
    if (i < 15) {
      xa[nxt][0] = *reinterpret_cast<const floatx4*>(xrow + (i + 1) * 32);
      xa[nxt][1] = *reinterpret_cast<const floatx4*>(xrow + (i + 1) * 32 + 4);
      int ksn = ks2 * 16 + i + 1;
#pragma unroll
      for (int nn = 0; nn < 6; ++nn)
        bfr[nxt][nn] = *reinterpret_cast<const short8*>(wp + (size_t)(ksn * 12 + n0 + nn) * 512);
    }
    uint4v aw;
    aw[0] = cvt_pk(xa[cur][0][0], xa[cur][0][1]);
    aw[1] = cvt_pk(xa[cur][0][2], xa[cur][0][3]);
    aw[2] = cvt_pk(xa[cur][1][0], xa[cur][1][1]);
    aw[3] = cvt_pk(xa[cur][1][2], xa[cur][1][3]);
    short8 af = __builtin_bit_cast(short8, aw);
#pragma unroll
    for (int nn = 0; nn < 6; ++nn)
      acc[nn] = __builtin_amdgcn_mfma_f32_16x16x32_bf16(af, bfr[cur][nn], acc[nn], 0, 0, 0);
  }

  if (ks2 == 1) {
#pragma unroll
    for (int nn = 0; nn < 6; ++nn)
      *reinterpret_cast<floatx4*>(&accS[ns][l][nn * 4]) = acc[nn];
  }
  __syncthreads();
  if (ks2 == 0) {
#pragma unroll
    for (int nn = 0; nn < 6; ++nn)
      acc[nn] += *reinterpret_cast<const floatx4*>(&accS[ns][l][nn * 4]);
#pragma unroll
    for (int nn = 0; nn < 6; ++nn) {
      int n = n0 + nn;
      int mat = n >> 2;
      int h = (n & 3) * 16 + lq;
      const float* bias = (mat == 0) ? bq : (mat == 1) ? bk : bv;
      float bias_f = bias[h];
      if (mat == 0) {          // q: pre-scale by 1/8
#pragma unroll
        for (int r = 0; r < 4; ++r)
          q[(size_t)(row0 + g * 4 + r) * Hn + h] = f2bf((acc[nn][r] + bias_f) * 0.125f);
      } else if (mat == 1) {
#pragma unroll
        for (int r = 0; r < 4; ++r)
          k[(size_t)(row0 + g * 4 + r) * Hn + h] = f2bf(acc[nn][r] + bias_f);
      } else {                 // v -> vT2[b][tile][h][32]
        int tile = chunk >> 1;
        int off = (chunk & 1) * 16 + g * 4;
        uint2v pk;
        pk[0] = cvt_pk(acc[nn][0] + bias_f, acc[nn][1] + bias_f);
        pk[1] = cvt_pk(acc[nn][2] + bias_f, acc[nn][3] + bias_f);
        *reinterpret_cast<uint2v*>(vT2 + (((size_t)batch * 64 + tile) * 64 + h) * 32 + off) = pk;
      }
    }
  }
}

// ---------------------------------------------------------------------------
// Kernel 2: flash attention — each wave computes 32 q-cols (2 sub-tiles) vs its
// 256-kv slice: 2x K/V reuse per load, half the VMEM instrs and L2 traffic.
// 512 blocks x 512 thr: 8 waves = 8-way KV split of one 32-q tile.
// K double-buffered; V single-buffered (covered by QK+softmax). No sched_barrier
// (source-level LDS dep is compiler-ordered; round-6 evidence: barrier cost +10us).
__global__ __launch_bounds__(512, 4) void k_attn(const ushort* __restrict__ qm,
                                                 const ushort* __restrict__ km,
                                                 const ushort* __restrict__ vT2,
                                                 const int* __restrict__ mask,
                                                 float* __restrict__ out) {
  __shared__ union SMem {
    ushort P[8][32 * 40];                          // per-wave P[q 32][kv 32 pad40] (20.5 KB)
    struct {
      float accS[4][64][36];                       // merge staging (36.9 KB)
      float mS[4][2][64];
      float lS[4][2][64];
    } mg;
  } sm;

  int tid = threadIdx.x;
  int l = tid & 63, w = tid >> 6;
  int s = w;                                       // kv-split 0..7
  int bid = blockIdx.x;
  int b = bid & 7;                                 // XCD-pinned batch
  int chunk = bid >> 3;                            // 0..63
  int q0 = chunk * 32;
  int lq = l & 15, g = l >> 4;

  // Q^T B-frags for both 16-q sub-tiles
  short8 qf[2][2];
#pragma unroll
  for (int qt2 = 0; qt2 < 2; ++qt2) {
    const ushort* qb = qm + ((size_t)(b * Tn + q0 + qt2 * 16 + lq)) * Hn + g * 8;
    qf[qt2][0] = *reinterpret_cast<const short8*>(qb);
    qf[qt2][1] = *reinterpret_cast<const short8*>(qb + 32);
  }

  const ushort* kp = km + ((size_t)(b * Tn + s * 256) + lq) * Hn + g * 8;      // + it*2048 + t*1024 + h*32
  const ushort* vp = vT2 + (((size_t)b * 64 + s * 8) * 64 + lq) * 32 + g * 8;  // + it*2048 + mt*512

  const int* mrow = mask + b * Tn + s * 256 + l;
  unsigned long long bal64[4];
#pragma unroll
  for (int j = 0; j < 4; ++j) bal64[j] = __ballot(mrow[j * 64] != 0);

  ushort* Pw = &sm.P[w][0];
  uint32_t* Pw32 = reinterpret_cast<uint32_t*>(Pw);

  float m[2] = {-1e30f, -1e30f};
  float lsum[2] = {0.f, 0.f};                      // per-lane partials
  floatx4 acc[2][4];
#pragma unroll
  for (int qt2 = 0; qt2 < 2; ++qt2)
#pragma unroll
    for (int mt = 0; mt < 4; ++mt) acc[qt2][mt] = (floatx4){0.f, 0.f, 0.f, 0.f};

  short8 kf[2][4];
#pragma unroll
  for (int t = 0; t < 2; ++t)
#pragma unroll
    for (int h = 0; h < 2; ++h)
      kf[0][t * 2 + h] = *reinterpret_cast<const short8*>(kp + t * 1024 + h * 32);

#pragma unroll
  for (int it = 0; it < 8; ++it) {
    const int cur = it & 1, nxt = cur ^ 1;
    if (it < 7) {                                  // prefetch next K tile
#pragma unroll
      for (int t = 0; t < 2; ++t)
#pragma unroll
        for (int h = 0; h < 2; ++h)
          kf[nxt][t * 2 + h] =
              *reinterpret_cast<const short8*>(kp + (it + 1) * 2048 + t * 1024 + h * 32);
    }
    short8 vf[4];                                  // V tile (consumed after softmax)
#pragma unroll
    for (int mt = 0; mt < 4; ++mt)
      vf[mt] = *reinterpret_cast<const short8*>(vp + it * 2048 + mt * 512);

    // ---- QK^T (S^T): lane holds q = qt2*16+lq (col), kv = t*16 + g*4 + r ----
    float sc[2][2][4];
#pragma unroll
    for (int qt2 = 0; qt2 < 2; ++qt2)
#pragma unroll
      for (int t = 0; t < 2; ++t) {
        floatx4 z = (floatx4){0.f, 0.f, 0.f, 0.f};
        z = __builtin_amdgcn_mfma_f32_16x16x32_bf16(kf[cur][t * 2 + 0], qf[qt2][0], z, 0, 0, 0);
        z = __builtin_amdgcn_mfma_f32_16x16x32_bf16(kf[cur][t * 2 + 1], qf[qt2][1], z, 0, 0, 0);
#pragma unroll
        for (int r = 0; r < 4; ++r) sc[qt2][t][r] = z[r];
      }
    // ---- mask (skipped when tile fully unmasked — wave-uniform test) ----
    unsigned int bal32 = (unsigned int)(bal64[it >> 1] >> ((it & 1) * 32));
    if (bal32 != 0xFFFFFFFFu) {
#pragma unroll
      for (int qt2 = 0; qt2 < 2; ++qt2)
#pragma unroll
        for (int t = 0; t < 2; ++t)
#pragma unroll
          for (int r = 0; r < 4; ++r)
            if (!((bal32 >> (t * 16 + g * 4 + r)) & 1u)) sc[qt2][t][r] = -1e9f;
    }
    // ---- per-lane maxes; rescale both sub-tiles only on growth > m+8 ----
    float pmax0 = fmaxf(fmaxf(fmaxf(sc[0][0][0], sc[0][0][1]), fmaxf(sc[0][0][2], sc[0][0][3])),
                        fmaxf(fmaxf(sc[0][1][0], sc[0][1][1]), fmaxf(sc[0][1][2], sc[0][1][3])));
    float pmax1 = fmaxf(fmaxf(fmaxf(sc[1][0][0], sc[1][0][1]), fmaxf(sc[1][0][2], sc[1][0][3])),
                        fmaxf(fmaxf(sc[1][1][0], sc[1][1][1]), fmaxf(sc[1][1][2], sc[1][1][3])));
    if (!__all((pmax0 - m[0] <= 8.0f) && (pmax1 - m[1] <= 8.0f))) {
      float rm0 = fmaxf(pmax0, __shfl_xor(pmax0, 16));
      rm0 = fmaxf(rm0, __shfl_xor(rm0, 32));
      float rm1 = fmaxf(pmax1, __shfl_xor(pmax1, 16));
      rm1 = fmaxf(rm1, __shfl_xor(rm1, 32));
      float mn0 = fmaxf(m[0], rm0), mn1 = fmaxf(m[1], rm1);
      float a0 = __builtin_amdgcn_exp2f((m[0] - mn0) * kLog2e);
      float a1 = __builtin_amdgcn_exp2f((m[1] - mn1) * kLog2e);
      lsum[0] *= a0; lsum[1] *= a1;
#pragma unroll
      for (int mt = 0; mt < 4; ++mt) { acc[0][mt] *= a0; acc[1][mt] *= a1; }
      m[0] = mn0; m[1] = mn1;
    }
    // ---- p = exp2(sc*k - m*k); write P LDS per sub-tile row ----
#pragma unroll
    for (int qt2 = 0; qt2 < 2; ++qt2) {
      float nmk = m[qt2] * kLog2e;
      float p[8];
#pragma unroll
      for (int t = 0; t < 2; ++t)
#pragma unroll
        for (int r = 0; r < 4; ++r)
          p[t * 4 + r] = __builtin_amdgcn_exp2f(__builtin_fmaf(sc[qt2][t][r], kLog2e, -nmk));
      lsum[qt2] += ((p[0] + p[1]) + (p[2] + p[3])) + ((p[4] + p[5]) + (p[6] + p[7]));
      uint2v pw0, pw1;
      pw0[0] = cvt_pk(p[0], p[1]); pw0[1] = cvt_pk(p[2], p[3]);
      pw1[0] = cvt_pk(p[4], p[5]); pw1[1] = cvt_pk(p[6], p[7]);
      int row = qt2 * 16 + lq;
      *reinterpret_cast<uint2v*>(Pw32 + row * 20 + g * 2) = pw0;
      *reinterpret_cast<uint2v*>(Pw32 + row * 20 + 8 + g * 2) = pw1;
    }
    // ---- PV: out^T += V^T @ P^T for both sub-tiles ----
    short8 pf0 = *reinterpret_cast<const short8*>(Pw + (0 * 16 + lq) * 40 + g * 8);
    short8 pf1 = *reinterpret_cast<const short8*>(Pw + (1 * 16 + lq) * 40 + g * 8);
#pragma unroll
    for (int mt = 0; mt < 4; ++mt) {
      acc[0][mt] = __builtin_amdgcn_mfma_f32_16x16x32_bf16(vf[mt], pf0, acc[0][mt], 0, 0, 0);
      acc[1][mt] = __builtin_amdgcn_mfma_f32_16x16x32_bf16(vf[mt], pf1, acc[1][mt], 0, 0, 0);
    }
  }

  // finalize per-row lsums (reduce per-lane partials over the 4 g-lanes)
#pragma unroll
  for (int qt2 = 0; qt2 < 2; ++qt2) {
    lsum[qt2] += __shfl_xor(lsum[qt2], 16);
    lsum[qt2] += __shfl_xor(lsum[qt2], 32);
  }

  // ---- two-stage merge of the 8 KV splits ----
  __syncthreads();                                 // P dead; safe to overwrite (union)
  if (s >= 4) {                                    // stage A: 4..7 stage
#pragma unroll
    for (int qt2 = 0; qt2 < 2; ++qt2) {
#pragma unroll
      for (int mt = 0; mt < 4; ++mt)
        *reinterpret_cast<floatx4*>(&sm.mg.accS[s - 4][l][qt2 * 16 + mt * 4]) = acc[qt2][mt];
      sm.mg.mS[s - 4][qt2][l] = m[qt2];
      sm.mg.lS[s - 4][qt2][l] = lsum[qt2];
    }
  }
  __syncthreads();
  if (s < 4) {                                     // absorb partner s+4
#pragma unroll
    for (int qt2 = 0; qt2 < 2; ++qt2) {
      float m2 = sm.mg.mS[s][qt2][l], l2 = sm.mg.lS[s][qt2][l];
      float mn = fmaxf(m[qt2], m2);
      float ea = __builtin_amdgcn_exp2f((m[qt2] - mn) * kLog2e);
      float eb = __builtin_amdgcn_exp2f((m2 - mn) * kLog2e);
      lsum[qt2] = lsum[qt2] * ea + l2 * eb;
#pragma unroll
      for (int mt = 0; mt < 4; ++mt) {
        floatx4 a = *reinterpret_cast<const floatx4*>(&sm.mg.accS[s][l][qt2 * 16 + mt * 4]);
#pragma unroll
        for (int r = 0; r < 4; ++r) acc[qt2][mt][r] = acc[qt2][mt][r] * ea + a[r] * eb;
      }
      m[qt2] = mn;
    }
  }
  __syncthreads();
  if (s >= 1 && s < 4) {                           // stage B: 1..3 stage
#pragma unroll
    for (int qt2 = 0; qt2 < 2; ++qt2) {
#pragma unroll
      for (int mt = 0; mt < 4; ++mt)
        *reinterpret_cast<floatx4*>(&sm.mg.accS[s - 1][l][qt2 * 16 + mt * 4]) = acc[qt2][mt];
      sm.mg.mS[s - 1][qt2][l] = m[qt2];
      sm.mg.lS[s - 1][qt2][l] = lsum[qt2];
    }
  }
  __syncthreads();
  if (s == 0) {                                    // wave 0 absorbs 3 + writes out
#pragma unroll
    for (int qt2 = 0; qt2 < 2; ++qt2) {
      float mtot = m[qt2];
#pragma unroll
      for (int si = 0; si < 3; ++si) mtot = fmaxf(mtot, sm.mg.mS[si][qt2][l]);
      float e0 = __builtin_amdgcn_exp2f((m[qt2] - mtot) * kLog2e);
      float ltot = lsum[qt2] * e0;
      float res[4][4];
#pragma unroll
      for (int mt = 0; mt < 4; ++mt)
#pragma unroll
        for (int r = 0; r < 4; ++r) res[mt][r] = acc[qt2][mt][r] * e0;
#pragma unroll
      for (int si = 0; si < 3; ++si) {
        float e = __builtin_amdgcn_exp2f((sm.mg.mS[si][qt2][l] - mtot) * kLog2e);
        ltot += sm.mg.lS[si][qt2][l] * e;
#pragma unroll
        for (int mt = 0; mt < 4; ++mt) {
          floatx4 a = *reinterpret_cast<const floatx4*>(&sm.mg.accS[si][l][qt2 * 16 + mt * 4]);
#pragma unroll
          for (int r = 0; r < 4; ++r) res[mt][r] += a[r] * e;
        }
      }
      float inv = 1.0f / ltot;
      float* obase = out + ((size_t)(b * Tn + q0 + qt2 * 16 + lq)) * Hn;
#pragma unroll
      for (int mt = 0; mt < 4; ++mt) {
        floatx4 o;
#pragma unroll
        for (int r = 0; r < 4; ++r) o[r] = res[mt][r] * inv;
        *reinterpret_cast<floatx4*>(obase + mt * 16 + g * 4) = o;
      }
    }
  }
}

// ---------------------------------------------------------------------------
extern "C" void kernel_launch(void* const* d_in, const int* in_sizes, int n_in,
                              void* d_out, int out_size, void* d_ws, size_t ws_size,
                              hipStream_t stream) {
  const float* x  = (const float*)d_in[0];
  const float* Wq = (const float*)d_in[1];
  const float* bq = (const float*)d_in[2];
  const float* Wk = (const float*)d_in[3];
  const float* bk = (const float*)d_in[4];
  const float* Wv = (const float*)d_in[5];
  const float* bv = (const float*)d_in[6];
  const int* mask = (const int*)d_in[7];
  float* outp = (float*)d_out;

  ushort* wpack = (ushort*)d_ws;                       // 384 KB
  ushort* qbuf  = wpack + 196608;                      // 2 MB bf16 (pre-scaled by 1/8)
  ushort* kbuf  = qbuf + (size_t)16384 * 64;           // 2 MB
  ushort* vT2   = kbuf + (size_t)16384 * 64;           // [8][64][64][32] bf16, 2 MB

  hipLaunchKernelGGL(k_packw, dim3(384), dim3(64), 0, stream, Wq, Wk, Wv, wpack);
  hipLaunchKernelGGL(k_qkv, dim3(1024), dim3(256), 0, stream, x, wpack, bq, bk, bv,
                     qbuf, kbuf, vT2);
  hipLaunchKernelGGL(k_attn, dim3(512), dim3(512), 0, stream, qbuf, kbuf, vT2, mask, outp);
}

// Round 11
// 65.077 us; speedup vs baseline: 1.4995x; 1.0654x over previous
//
#include <hip/hip_runtime.h>
#include <hip/hip_bf16.h>
#include <stdint.h>

// AttentionHead: x[8,2048,1024](f32) @ {Wq,Wk,Wv}[1024,64](f32) + bias -> flash attn -> out[8,2048,64](f32)
// f32 I/O; internal q/k/vT scratch bf16 (q pre-scaled by 1/8); f32 accumulation.
// XCD-pinned: batch b lives on XCD b (bid & 7) for producer and consumer.

typedef __attribute__((ext_vector_type(8))) short short8;   // 8 bf16 (MFMA A/B frag)
typedef __attribute__((ext_vector_type(4))) float floatx4;  // MFMA C/D frag / 16B f32
typedef __attribute__((ext_vector_type(2))) uint32_t uint2v;
typedef __attribute__((ext_vector_type(4))) uint32_t uint4v;

static constexpr int Tn = 2048, En = 1024, Hn = 64;
static constexpr float kLog2e = 1.44269504088896340736f;

static __device__ __forceinline__ ushort f2bf(float f) {
  uint32_t u = __builtin_bit_cast(uint32_t, f);
  u += 0x7FFFu + ((u >> 16) & 1u);          // RNE
  return (ushort)(u >> 16);
}
static __device__ __forceinline__ uint32_t cvt_pk(float lo, float hi) {
  uint32_t r;
  asm("v_cvt_pk_bf16_f32 %0, %1, %2" : "=v"(r) : "v"(lo), "v"(hi));
  return r;
}

// ---------------------------------------------------------------------------
// Kernel 0: pack Wq|Wk|Wv (f32) into bf16 B-fragment order.
__global__ __launch_bounds__(64) void k_packw(const float* __restrict__ Wq,
                                              const float* __restrict__ Wk,
                                              const float* __restrict__ Wv,
                                              ushort* __restrict__ wpack) {
  int blk = blockIdx.x;
  int kstep = blk / 12, ntile = blk % 12;
  int l = threadIdx.x;
  const float* W = (ntile < 4) ? Wq : (ntile < 8) ? Wk : Wv;
  int col = (ntile & 3) * 16 + (l & 15);
  int k0 = kstep * 32 + (l >> 4) * 8;
  short8 v;
#pragma unroll
  for (int j = 0; j < 8; ++j) v[j] = (short)f2bf(W[(k0 + j) * Hn + col]);
  *reinterpret_cast<short8*>(wpack + ((size_t)(kstep * 12 + ntile) * 64 + l) * 8) = v;
}

// ---------------------------------------------------------------------------
// Kernel 1: QKV projection v3 — LDS-staged x (bf16), minimal register state.
// 1024 blocks x 256 thr (4 waves). Stage 16x1024 x-tile to LDS once; each wave
// then computes 3 whole n-tiles over full K=1024 (no cross-wave merge).
// Inner loop live state ~45 VGPR: robust against allocator heuristics.
__global__ __launch_bounds__(256) void k_qkv(const float* __restrict__ x,
                                             const ushort* __restrict__ wpack,
                                             const float* __restrict__ bq,
                                             const float* __restrict__ bk,
                                             const float* __restrict__ bv,
                                             ushort* __restrict__ q,
                                             ushort* __restrict__ k,
                                             ushort* __restrict__ vT2) {
  __shared__ ushort xs[16][1032];       // bf16 x-tile, +8 pad (16B-aligned rows, bank-balanced)
  int tid = threadIdx.x;
  int batch = blockIdx.x & 7;           // XCD-pinned
  int chunk = blockIdx.x >> 3;          // 0..127
  int row0 = batch * Tn + chunk * 16;

  // ---- stage x tile: 16 rows x 1024 f32 -> bf16 LDS (one barrier) ----
  {
    int r = tid & 15;                   // row
    int kc = tid >> 4;                  // 64-float chunk 0..15
    const float* src = x + (size_t)(row0 + r) * En + kc * 64;
    ushort* dst = &xs[r][kc * 64];
#pragma unroll
    for (int i = 0; i < 16; ++i) {
      floatx4 f = *reinterpret_cast<const floatx4*>(src + i * 4);
      uint2v u;
      u[0] = cvt_pk(f[0], f[1]);
      u[1] = cvt_pk(f[2], f[3]);
      *reinterpret_cast<uint2v*>(dst + i * 4) = u;
    }
  }
  __syncthreads();

  int l = tid & 63;
  int w = tid >> 6;                     // wave 0..3 -> n-tiles w*3..w*3+2
  int lq = l & 15, g = l >> 4;

#pragma unroll
  for (int nn = 0; nn < 3; ++nn) {
    int n = w * 3 + nn;
    const ushort* wpn = wpack + ((size_t)n * 64 + l) * 8;   // + ks*6144
    floatx4 acc = (floatx4){0.f, 0.f, 0.f, 0.f};
#pragma unroll 4
    for (int ks = 0; ks < 32; ++ks) {
      short8 af = *reinterpret_cast<const short8*>(&xs[lq][ks * 32 + g * 8]);
      short8 bf = *reinterpret_cast<const short8*>(wpn + (size_t)ks * 6144);
      acc = __builtin_amdgcn_mfma_f32_16x16x32_bf16(af, bf, acc, 0, 0, 0);
    }
    // epilogue: C/D frag col = lane&15, row = (lane>>4)*4 + r
    int mat = n >> 2;
    int h = (n & 3) * 16 + lq;
    const float* bias = (mat == 0) ? bq : (mat == 1) ? bk : bv;
    float bias_f = bias[h];
    if (mat == 0) {            // q: pre-scale by 1/8 (softmax scale folded in)
#pragma unroll
      for (int r = 0; r < 4; ++r)
        q[(size_t)(row0 + g * 4 + r) * Hn + h] = f2bf((acc[r] + bias_f) * 0.125f);
    } else if (mat == 1) {
#pragma unroll
      for (int r = 0; r < 4; ++r)
        k[(size_t)(row0 + g * 4 + r) * Hn + h] = f2bf(acc[r] + bias_f);
    } else {                   // v -> vT2[b][tile][h][32]
      int tile = chunk >> 1;
      int off = (chunk & 1) * 16 + g * 4;
      uint2v pk;
      pk[0] = cvt_pk(acc[0] + bias_f, acc[1] + bias_f);
      pk[1] = cvt_pk(acc[2] + bias_f, acc[3] + bias_f);
      *reinterpret_cast<uint2v*>(vT2 + (((size_t)batch * 64 + tile) * 64 + h) * 32 + off) = pk;
    }
  }
}

// ---------------------------------------------------------------------------
// Kernel 2: flash attention — round-10 passing structure, UNCHANGED.
// Each wave computes 32 q-cols (2 sub-tiles) vs its 256-kv slice.
// 512 blocks x 512 thr: 8 waves = 8-way KV split of one 32-q tile.
__global__ __launch_bounds__(512, 4) void k_attn(const ushort* __restrict__ qm,
                                                 const ushort* __restrict__ km,
                                                 const ushort* __restrict__ vT2,
                                                 const int* __restrict__ mask,
                                                 float* __restrict__ out) {
  __shared__ union SMem {
    ushort P[8][32 * 40];                          // per-wave P[q 32][kv 32 pad40] (20.5 KB)
    struct {
      float accS[4][64][36];                       // merge staging (36.9 KB)
      float mS[4][2][64];
      float lS[4][2][64];
    } mg;
  } sm;

  int tid = threadIdx.x;
  int l = tid & 63, w = tid >> 6;
  int s = w;                                       // kv-split 0..7
  int bid = blockIdx.x;
  int b = bid & 7;                                 // XCD-pinned batch
  int chunk = bid >> 3;                            // 0..63
  int q0 = chunk * 32;
  int lq = l & 15, g = l >> 4;

  // Q^T B-frags for both 16-q sub-tiles
  short8 qf[2][2];
#pragma unroll
  for (int qt2 = 0; qt2 < 2; ++qt2) {
    const ushort* qb = qm + ((size_t)(b * Tn + q0 + qt2 * 16 + lq)) * Hn + g * 8;
    qf[qt2][0] = *reinterpret_cast<const short8*>(qb);
    qf[qt2][1] = *reinterpret_cast<const short8*>(qb + 32);
  }

  const ushort* kp = km + ((size_t)(b * Tn + s * 256) + lq) * Hn + g * 8;      // + it*2048 + t*1024 + h*32
  const ushort* vp = vT2 + (((size_t)b * 64 + s * 8) * 64 + lq) * 32 + g * 8;  // + it*2048 + mt*512

  const int* mrow = mask + b * Tn + s * 256 + l;
  unsigned long long bal64[4];
#pragma unroll
  for (int j = 0; j < 4; ++j) bal64[j] = __ballot(mrow[j * 64] != 0);

  ushort* Pw = &sm.P[w][0];
  uint32_t* Pw32 = reinterpret_cast<uint32_t*>(Pw);

  float m[2] = {-1e30f, -1e30f};
  float lsum[2] = {0.f, 0.f};                      // per-lane partials
  floatx4 acc[2][4];
#pragma unroll
  for (int qt2 = 0; qt2 < 2; ++qt2)
#pragma unroll
    for (int mt = 0; mt < 4; ++mt) acc[qt2][mt] = (floatx4){0.f, 0.f, 0.f, 0.f};

  short8 kf[2][4];
#pragma unroll
  for (int t = 0; t < 2; ++t)
#pragma unroll
    for (int h = 0; h < 2; ++h)
      kf[0][t * 2 + h] = *reinterpret_cast<const short8*>(kp + t * 1024 + h * 32);

#pragma unroll
  for (int it = 0; it < 8; ++it) {
    const int cur = it & 1, nxt = cur ^ 1;
    if (it < 7) {                                  // prefetch next K tile
#pragma unroll
      for (int t = 0; t < 2; ++t)
#pragma unroll
        for (int h = 0; h < 2; ++h)
          kf[nxt][t * 2 + h] =
              *reinterpret_cast<const short8*>(kp + (it + 1) * 2048 + t * 1024 + h * 32);
    }
    short8 vf[4];                                  // V tile (consumed after softmax)
#pragma unroll
    for (int mt = 0; mt < 4; ++mt)
      vf[mt] = *reinterpret_cast<const short8*>(vp + it * 2048 + mt * 512);

    // ---- QK^T (S^T): lane holds q = qt2*16+lq (col), kv = t*16 + g*4 + r ----
    float sc[2][2][4];
#pragma unroll
    for (int qt2 = 0; qt2 < 2; ++qt2)
#pragma unroll
      for (int t = 0; t < 2; ++t) {
        floatx4 z = (floatx4){0.f, 0.f, 0.f, 0.f};
        z = __builtin_amdgcn_mfma_f32_16x16x32_bf16(kf[cur][t * 2 + 0], qf[qt2][0], z, 0, 0, 0);
        z = __builtin_amdgcn_mfma_f32_16x16x32_bf16(kf[cur][t * 2 + 1], qf[qt2][1], z, 0, 0, 0);
#pragma unroll
        for (int r = 0; r < 4; ++r) sc[qt2][t][r] = z[r];
      }
    // ---- mask (skipped when tile fully unmasked — wave-uniform test) ----
    unsigned int bal32 = (unsigned int)(bal64[it >> 1] >> ((it & 1) * 32));
    if (bal32 != 0xFFFFFFFFu) {
#pragma unroll
      for (int qt2 = 0; qt2 < 2; ++qt2)
#pragma unroll
        for (int t = 0; t < 2; ++t)
#pragma unroll
          for (int r = 0; r < 4; ++r)
            if (!((bal32 >> (t * 16 + g * 4 + r)) & 1u)) sc[qt2][t][r] = -1e9f;
    }
    // ---- per-lane maxes; rescale both sub-tiles only on growth > m+8 ----
    float pmax0 = fmaxf(fmaxf(fmaxf(sc[0][0][0], sc[0][0][1]), fmaxf(sc[0][0][2], sc[0][0][3])),
                        fmaxf(fmaxf(sc[0][1][0], sc[0][1][1]), fmaxf(sc[0][1][2], sc[0][1][3])));
    float pmax1 = fmaxf(fmaxf(fmaxf(sc[1][0][0], sc[1][0][1]), fmaxf(sc[1][0][2], sc[1][0][3])),
                        fmaxf(fmaxf(sc[1][1][0], sc[1][1][1]), fmaxf(sc[1][1][2], sc[1][1][3])));
    if (!__all((pmax0 - m[0] <= 8.0f) && (pmax1 - m[1] <= 8.0f))) {
      float rm0 = fmaxf(pmax0, __shfl_xor(pmax0, 16));
      rm0 = fmaxf(rm0, __shfl_xor(rm0, 32));
      float rm1 = fmaxf(pmax1, __shfl_xor(pmax1, 16));
      rm1 = fmaxf(rm1, __shfl_xor(rm1, 32));
      float mn0 = fmaxf(m[0], rm0), mn1 = fmaxf(m[1], rm1);
      float a0 = __builtin_amdgcn_exp2f((m[0] - mn0) * kLog2e);
      float a1 = __builtin_amdgcn_exp2f((m[1] - mn1) * kLog2e);
      lsum[0] *= a0; lsum[1] *= a1;
#pragma unroll
      for (int mt = 0; mt < 4; ++mt) { acc[0][mt] *= a0; acc[1][mt] *= a1; }
      m[0] = mn0; m[1] = mn1;
    }
    // ---- p = exp2(sc*k - m*k); write P LDS per sub-tile row ----
#pragma unroll
    for (int qt2 = 0; qt2 < 2; ++qt2) {
      float nmk = m[qt2] * kLog2e;
      float p[8];
#pragma unroll
      for (int t = 0; t < 2; ++t)
#pragma unroll
        for (int r = 0; r < 4; ++r)
          p[t * 4 + r] = __builtin_amdgcn_exp2f(__builtin_fmaf(sc[qt2][t][r], kLog2e, -nmk));
      lsum[qt2] += ((p[0] + p[1]) + (p[2] + p[3])) + ((p[4] + p[5]) + (p[6] + p[7]));
      uint2v pw0, pw1;
      pw0[0] = cvt_pk(p[0], p[1]); pw0[1] = cvt_pk(p[2], p[3]);
      pw1[0] = cvt_pk(p[4], p[5]); pw1[1] = cvt_pk(p[6], p[7]);
      int row = qt2 * 16 + lq;
      *reinterpret_cast<uint2v*>(Pw32 + row * 20 + g * 2) = pw0;
      *reinterpret_cast<uint2v*>(Pw32 + row * 20 + 8 + g * 2) = pw1;
    }
    // ---- PV: out^T += V^T @ P^T for both sub-tiles ----
    short8 pf0 = *reinterpret_cast<const short8*>(Pw + (0 * 16 + lq) * 40 + g * 8);
    short8 pf1 = *reinterpret_cast<const short8*>(Pw + (1 * 16 + lq) * 40 + g * 8);
#pragma unroll
    for (int mt = 0; mt < 4; ++mt) {
      acc[0][mt] = __builtin_amdgcn_mfma_f32_16x16x32_bf16(vf[mt], pf0, acc[0][mt], 0, 0, 0);
      acc[1][mt] = __builtin_amdgcn_mfma_f32_16x16x32_bf16(vf[mt], pf1, acc[1][mt], 0, 0, 0);
    }
  }

  // finalize per-row lsums (reduce per-lane partials over the 4 g-lanes)
#pragma unroll
  for (int qt2 = 0; qt2 < 2; ++qt2) {
    lsum[qt2] += __shfl_xor(lsum[qt2], 16);
    lsum[qt2] += __shfl_xor(lsum[qt2], 32);
  }

  // ---- two-stage merge of the 8 KV splits ----
  __syncthreads();                                 // P dead; safe to overwrite (union)
  if (s >= 4) {                                    // stage A: 4..7 stage
#pragma unroll
    for (int qt2 = 0; qt2 < 2; ++qt2) {
#pragma unroll
      for (int mt = 0; mt < 4; ++mt)
        *reinterpret_cast<floatx4*>(&sm.mg.accS[s - 4][l][qt2 * 16 + mt * 4]) = acc[qt2][mt];
      sm.mg.mS[s - 4][qt2][l] = m[qt2];
      sm.mg.lS[s - 4][qt2][l] = lsum[qt2];
    }
  }
  __syncthreads();
  if (s < 4) {                                     // absorb partner s+4
#pragma unroll
    for (int qt2 = 0; qt2 < 2; ++qt2) {
      float m2 = sm.mg.mS[s][qt2][l], l2 = sm.mg.lS[s][qt2][l];
      float mn = fmaxf(m[qt2], m2);
      float ea = __builtin_amdgcn_exp2f((m[qt2] - mn) * kLog2e);
      float eb = __builtin_amdgcn_exp2f((m2 - mn) * kLog2e);
      lsum[qt2] = lsum[qt2] * ea + l2 * eb;
#pragma unroll
      for (int mt = 0; mt < 4; ++mt) {
        floatx4 a = *reinterpret_cast<const floatx4*>(&sm.mg.accS[s][l][qt2 * 16 + mt * 4]);
#pragma unroll
        for (int r = 0; r < 4; ++r) acc[qt2][mt][r] = acc[qt2][mt][r] * ea + a[r] * eb;
      }
      m[qt2] = mn;
    }
  }
  __syncthreads();
  if (s >= 1 && s < 4) {                           // stage B: 1..3 stage
#pragma unroll
    for (int qt2 = 0; qt2 < 2; ++qt2) {
#pragma unroll
      for (int mt = 0; mt < 4; ++mt)
        *reinterpret_cast<floatx4*>(&sm.mg.accS[s - 1][l][qt2 * 16 + mt * 4]) = acc[qt2][mt];
      sm.mg.mS[s - 1][qt2][l] = m[qt2];
      sm.mg.lS[s - 1][qt2][l] = lsum[qt2];
    }
  }
  __syncthreads();
  if (s == 0) {                                    // wave 0 absorbs 3 + writes out
#pragma unroll
    for (int qt2 = 0; qt2 < 2; ++qt2) {
      float mtot = m[qt2];
#pragma unroll
      for (int si = 0; si < 3; ++si) mtot = fmaxf(mtot, sm.mg.mS[si][qt2][l]);
      float e0 = __builtin_amdgcn_exp2f((m[qt2] - mtot) * kLog2e);
      float ltot = lsum[qt2] * e0;
      float res[4][4];
#pragma unroll
      for (int mt = 0; mt < 4; ++mt)
#pragma unroll
        for (int r = 0; r < 4; ++r) res[mt][r] = acc[qt2][mt][r] * e0;
#pragma unroll
      for (int si = 0; si < 3; ++si) {
        float e = __builtin_amdgcn_exp2f((sm.mg.mS[si][qt2][l] - mtot) * kLog2e);
        ltot += sm.mg.lS[si][qt2][l] * e;
#pragma unroll
        for (int mt = 0; mt < 4; ++mt) {
          floatx4 a = *reinterpret_cast<const floatx4*>(&sm.mg.accS[si][l][qt2 * 16 + mt * 4]);
#pragma unroll
          for (int r = 0; r < 4; ++r) res[mt][r] += a[r] * e;
        }
      }
      float inv = 1.0f / ltot;
      float* obase = out + ((size_t)(b * Tn + q0 + qt2 * 16 + lq)) * Hn;
#pragma unroll
      for (int mt = 0; mt < 4; ++mt) {
        floatx4 o;
#pragma unroll
        for (int r = 0; r < 4; ++r) o[r] = res[mt][r] * inv;
        *reinterpret_cast<floatx4*>(obase + mt * 16 + g * 4) = o;
      }
    }
  }
}

// ---------------------------------------------------------------------------
extern "C" void kernel_launch(void* const* d_in, const int* in_sizes, int n_in,
                              void* d_out, int out_size, void* d_ws, size_t ws_size,
                              hipStream_t stream) {
  const float* x  = (const float*)d_in[0];
  const float* Wq = (const float*)d_in[1];
  const float* bq = (const float*)d_in[2];
  const float* Wk = (const float*)d_in[3];
  const float* bk = (const float*)d_in[4];
  const float* Wv = (const float*)d_in[5];
  const float* bv = (const float*)d_in[6];
  const int* mask = (const int*)d_in[7];
  float* outp = (float*)d_out;

  ushort* wpack = (ushort*)d_ws;                       // 384 KB
  ushort* qbuf  = wpack + 196608;                      // 2 MB bf16 (pre-scaled by 1/8)
  ushort* kbuf  = qbuf + (size_t)16384 * 64;           // 2 MB
  ushort* vT2   = kbuf + (size_t)16384 * 64;           // [8][64][64][32] bf16, 2 MB

  hipLaunchKernelGGL(k_packw, dim3(384), dim3(64), 0, stream, Wq, Wk, Wv, wpack);
  hipLaunchKernelGGL(k_qkv, dim3(1024), dim3(256), 0, stream, x, wpack, bq, bk, bv,
                     qbuf, kbuf, vT2);
  hipLaunchKernelGGL(k_attn, dim3(512), dim3(512), 0, stream, qbuf, kbuf, vT2, mask, outp);
}

// Round 12
// 65.030 us; speedup vs baseline: 1.5005x; 1.0007x over previous
//
#include <hip/hip_runtime.h>
#include <hip/hip_bf16.h>
#include <stdint.h>

// AttentionHead: x[8,2048,1024](f32) @ {Wq,Wk,Wv}[1024,64](f32) + bias -> flash attn -> out[8,2048,64](f32)
// f32 I/O; internal q/k/vT scratch bf16 (q pre-scaled by 1/8); f32 accumulation.
// XCD-pinned: batch b lives on XCD b (bid & 7) for producer and consumer.

typedef __attribute__((ext_vector_type(8))) short short8;   // 8 bf16 (MFMA A/B frag)
typedef __attribute__((ext_vector_type(4))) float floatx4;  // MFMA C/D frag / 16B f32
typedef __attribute__((ext_vector_type(2))) uint32_t uint2v;
typedef __attribute__((ext_vector_type(4))) uint32_t uint4v;

static constexpr int Tn = 2048, En = 1024, Hn = 64;
static constexpr float kLog2e = 1.44269504088896340736f;

static __device__ __forceinline__ ushort f2bf(float f) {
  uint32_t u = __builtin_bit_cast(uint32_t, f);
  u += 0x7FFFu + ((u >> 16) & 1u);          // RNE
  return (ushort)(u >> 16);
}
static __device__ __forceinline__ uint32_t cvt_pk(float lo, float hi) {
  uint32_t r;
  asm("v_cvt_pk_bf16_f32 %0, %1, %2" : "=v"(r) : "v"(lo), "v"(hi));
  return r;
}

// ---------------------------------------------------------------------------
// Kernel 0: pack Wq|Wk|Wv (f32) into bf16 B-fragment order.
__global__ __launch_bounds__(64) void k_packw(const float* __restrict__ Wq,
                                              const float* __restrict__ Wk,
                                              const float* __restrict__ Wv,
                                              ushort* __restrict__ wpack) {
  int blk = blockIdx.x;
  int kstep = blk / 12, ntile = blk % 12;
  int l = threadIdx.x;
  const float* W = (ntile < 4) ? Wq : (ntile < 8) ? Wk : Wv;
  int col = (ntile & 3) * 16 + (l & 15);
  int k0 = kstep * 32 + (l >> 4) * 8;
  short8 v;
#pragma unroll
  for (int j = 0; j < 8; ++j) v[j] = (short)f2bf(W[(k0 + j) * Hn + col]);
  *reinterpret_cast<short8*>(wpack + ((size_t)(kstep * 12 + ntile) * 64 + l) * 8) = v;
}

// ---------------------------------------------------------------------------
// Kernel 1: QKV projection v4 — LDS-staged x (bf16) with COALESCED staging
// (one full row per step, lane-adjacent 16B) and ks-outer/nn-inner compute
// (3 independent MFMA chains, af ds_read reused 3x, 12 L2 loads in flight).
// 1024 blocks x 256 thr (4 waves); wave w owns n-tiles w*3..w*3+2 over K=1024.
__global__ __launch_bounds__(256) void k_qkv(const float* __restrict__ x,
                                             const ushort* __restrict__ wpack,
                                             const float* __restrict__ bq,
                                             const float* __restrict__ bk,
                                             const float* __restrict__ bv,
                                             ushort* __restrict__ q,
                                             ushort* __restrict__ k,
                                             ushort* __restrict__ vT2) {
  __shared__ ushort xs[16][1032];       // bf16 x-tile, +8 pad (16B-aligned rows)
  int tid = threadIdx.x;
  int batch = blockIdx.x & 7;           // XCD-pinned
  int chunk = blockIdx.x >> 3;          // 0..127
  int row0 = batch * Tn + chunk * 16;

  // ---- stage x tile: row i per step, 256 thr x float4 = 4KB contiguous ----
  {
    const float* src = x + (size_t)row0 * En + tid * 4;
#pragma unroll
    for (int i = 0; i < 16; ++i) {
      floatx4 f = *reinterpret_cast<const floatx4*>(src + (size_t)i * En);
      uint2v u;
      u[0] = cvt_pk(f[0], f[1]);
      u[1] = cvt_pk(f[2], f[3]);
      *reinterpret_cast<uint2v*>(&xs[i][tid * 4]) = u;
    }
  }
  __syncthreads();

  int l = tid & 63;
  int w = tid >> 6;                     // wave 0..3 -> n-tiles w*3..w*3+2
  int lq = l & 15, g = l >> 4;
  const ushort* wpn = wpack + (((size_t)w * 3) * 64 + l) * 8;  // + ks*6144 + nn*512 (halves)

  floatx4 acc[3];
#pragma unroll
  for (int nn = 0; nn < 3; ++nn) acc[nn] = (floatx4){0.f, 0.f, 0.f, 0.f};

#pragma unroll 4
  for (int ks = 0; ks < 32; ++ks) {
    short8 af = *reinterpret_cast<const short8*>(&xs[lq][ks * 32 + g * 8]);
#pragma unroll
    for (int nn = 0; nn < 3; ++nn) {
      short8 bf = *reinterpret_cast<const short8*>(wpn + (size_t)ks * 6144 + nn * 512);
      acc[nn] = __builtin_amdgcn_mfma_f32_16x16x32_bf16(af, bf, acc[nn], 0, 0, 0);
    }
  }

  // epilogue: C/D frag col = lane&15, row = (lane>>4)*4 + r
#pragma unroll
  for (int nn = 0; nn < 3; ++nn) {
    int n = w * 3 + nn;
    int mat = n >> 2;
    int h = (n & 3) * 16 + lq;
    const float* bias = (mat == 0) ? bq : (mat == 1) ? bk : bv;
    float bias_f = bias[h];
    if (mat == 0) {            // q: pre-scale by 1/8 (softmax scale folded in)
#pragma unroll
      for (int r = 0; r < 4; ++r)
        q[(size_t)(row0 + g * 4 + r) * Hn + h] = f2bf((acc[nn][r] + bias_f) * 0.125f);
    } else if (mat == 1) {
#pragma unroll
      for (int r = 0; r < 4; ++r)
        k[(size_t)(row0 + g * 4 + r) * Hn + h] = f2bf(acc[nn][r] + bias_f);
    } else {                   // v -> vT2[b][tile][h][32]
      int tile = chunk >> 1;
      int off = (chunk & 1) * 16 + g * 4;
      uint2v pk;
      pk[0] = cvt_pk(acc[nn][0] + bias_f, acc[nn][1] + bias_f);
      pk[1] = cvt_pk(acc[nn][2] + bias_f, acc[nn][3] + bias_f);
      *reinterpret_cast<uint2v*>(vT2 + (((size_t)batch * 64 + tile) * 64 + h) * 32 + off) = pk;
    }
  }
}

// ---------------------------------------------------------------------------
// Kernel 2: flash attention — round-10 passing structure, UNCHANGED.
// Each wave computes 32 q-cols (2 sub-tiles) vs its 256-kv slice.
// 512 blocks x 512 thr: 8 waves = 8-way KV split of one 32-q tile.
__global__ __launch_bounds__(512, 4) void k_attn(const ushort* __restrict__ qm,
                                                 const ushort* __restrict__ km,
                                                 const ushort* __restrict__ vT2,
                                                 const int* __restrict__ mask,
                                                 float* __restrict__ out) {
  __shared__ union SMem {
    ushort P[8][32 * 40];                          // per-wave P[q 32][kv 32 pad40] (20.5 KB)
    struct {
      float accS[4][64][36];                       // merge staging (36.9 KB)
      float mS[4][2][64];
      float lS[4][2][64];
    } mg;
  } sm;

  int tid = threadIdx.x;
  int l = tid & 63, w = tid >> 6;
  int s = w;                                       // kv-split 0..7
  int bid = blockIdx.x;
  int b = bid & 7;                                 // XCD-pinned batch
  int chunk = bid >> 3;                            // 0..63
  int q0 = chunk * 32;
  int lq = l & 15, g = l >> 4;

  // Q^T B-frags for both 16-q sub-tiles
  short8 qf[2][2];
#pragma unroll
  for (int qt2 = 0; qt2 < 2; ++qt2) {
    const ushort* qb = qm + ((size_t)(b * Tn + q0 + qt2 * 16 + lq)) * Hn + g * 8;
    qf[qt2][0] = *reinterpret_cast<const short8*>(qb);
    qf[qt2][1] = *reinterpret_cast<const short8*>(qb + 32);
  }

  const ushort* kp = km + ((size_t)(b * Tn + s * 256) + lq) * Hn + g * 8;      // + it*2048 + t*1024 + h*32
  const ushort* vp = vT2 + (((size_t)b * 64 + s * 8) * 64 + lq) * 32 + g * 8;  // + it*2048 + mt*512

  const int* mrow = mask + b * Tn + s * 256 + l;
  unsigned long long bal64[4];
#pragma unroll
  for (int j = 0; j < 4; ++j) bal64[j] = __ballot(mrow[j * 64] != 0);

  ushort* Pw = &sm.P[w][0];
  uint32_t* Pw32 = reinterpret_cast<uint32_t*>(Pw);

  float m[2] = {-1e30f, -1e30f};
  float lsum[2] = {0.f, 0.f};                      // per-lane partials
  floatx4 acc[2][4];
#pragma unroll
  for (int qt2 = 0; qt2 < 2; ++qt2)
#pragma unroll
    for (int mt = 0; mt < 4; ++mt) acc[qt2][mt] = (floatx4){0.f, 0.f, 0.f, 0.f};

  short8 kf[2][4];
#pragma unroll
  for (int t = 0; t < 2; ++t)
#pragma unroll
    for (int h = 0; h < 2; ++h)
      kf[0][t * 2 + h] = *reinterpret_cast<const short8*>(kp + t * 1024 + h * 32);

#pragma unroll
  for (int it = 0; it < 8; ++it) {
    const int cur = it & 1, nxt = cur ^ 1;
    if (it < 7) {                                  // prefetch next K tile
#pragma unroll
      for (int t = 0; t < 2; ++t)
#pragma unroll
        for (int h = 0; h < 2; ++h)
          kf[nxt][t * 2 + h] =
              *reinterpret_cast<const short8*>(kp + (it + 1) * 2048 + t * 1024 + h * 32);
    }
    short8 vf[4];                                  // V tile (consumed after softmax)
#pragma unroll
    for (int mt = 0; mt < 4; ++mt)
      vf[mt] = *reinterpret_cast<const short8*>(vp + it * 2048 + mt * 512);

    // ---- QK^T (S^T): lane holds q = qt2*16+lq (col), kv = t*16 + g*4 + r ----
    float sc[2][2][4];
#pragma unroll
    for (int qt2 = 0; qt2 < 2; ++qt2)
#pragma unroll
      for (int t = 0; t < 2; ++t) {
        floatx4 z = (floatx4){0.f, 0.f, 0.f, 0.f};
        z = __builtin_amdgcn_mfma_f32_16x16x32_bf16(kf[cur][t * 2 + 0], qf[qt2][0], z, 0, 0, 0);
        z = __builtin_amdgcn_mfma_f32_16x16x32_bf16(kf[cur][t * 2 + 1], qf[qt2][1], z, 0, 0, 0);
#pragma unroll
        for (int r = 0; r < 4; ++r) sc[qt2][t][r] = z[r];
      }
    // ---- mask (skipped when tile fully unmasked — wave-uniform test) ----
    unsigned int bal32 = (unsigned int)(bal64[it >> 1] >> ((it & 1) * 32));
    if (bal32 != 0xFFFFFFFFu) {
#pragma unroll
      for (int qt2 = 0; qt2 < 2; ++qt2)
#pragma unroll
        for (int t = 0; t < 2; ++t)
#pragma unroll
          for (int r = 0; r < 4; ++r)
            if (!((bal32 >> (t * 16 + g * 4 + r)) & 1u)) sc[qt2][t][r] = -1e9f;
    }
    // ---- per-lane maxes; rescale both sub-tiles only on growth > m+8 ----
    float pmax0 = fmaxf(fmaxf(fmaxf(sc[0][0][0], sc[0][0][1]), fmaxf(sc[0][0][2], sc[0][0][3])),
                        fmaxf(fmaxf(sc[0][1][0], sc[0][1][1]), fmaxf(sc[0][1][2], sc[0][1][3])));
    float pmax1 = fmaxf(fmaxf(fmaxf(sc[1][0][0], sc[1][0][1]), fmaxf(sc[1][0][2], sc[1][0][3])),
                        fmaxf(fmaxf(sc[1][1][0], sc[1][1][1]), fmaxf(sc[1][1][2], sc[1][1][3])));
    if (!__all((pmax0 - m[0] <= 8.0f) && (pmax1 - m[1] <= 8.0f))) {
      float rm0 = fmaxf(pmax0, __shfl_xor(pmax0, 16));
      rm0 = fmaxf(rm0, __shfl_xor(rm0, 32));
      float rm1 = fmaxf(pmax1, __shfl_xor(pmax1, 16));
      rm1 = fmaxf(rm1, __shfl_xor(rm1, 32));
      float mn0 = fmaxf(m[0], rm0), mn1 = fmaxf(m[1], rm1);
      float a0 = __builtin_amdgcn_exp2f((m[0] - mn0) * kLog2e);
      float a1 = __builtin_amdgcn_exp2f((m[1] - mn1) * kLog2e);
      lsum[0] *= a0; lsum[1] *= a1;
#pragma unroll
      for (int mt = 0; mt < 4; ++mt) { acc[0][mt] *= a0; acc[1][mt] *= a1; }
      m[0] = mn0; m[1] = mn1;
    }
    // ---- p = exp2(sc*k - m*k); write P LDS per sub-tile row ----
#pragma unroll
    for (int qt2 = 0; qt2 < 2; ++qt2) {
      float nmk = m[qt2] * kLog2e;
      float p[8];
#pragma unroll
      for (int t = 0; t < 2; ++t)
#pragma unroll
        for (int r = 0; r < 4; ++r)
          p[t * 4 + r] = __builtin_amdgcn_exp2f(__builtin_fmaf(sc[qt2][t][r], kLog2e, -nmk));
      lsum[qt2] += ((p[0] + p[1]) + (p[2] + p[3])) + ((p[4] + p[5]) + (p[6] + p[7]));
      uint2v pw0, pw1;
      pw0[0] = cvt_pk(p[0], p[1]); pw0[1] = cvt_pk(p[2], p[3]);
      pw1[0] = cvt_pk(p[4], p[5]); pw1[1] = cvt_pk(p[6], p[7]);
      int row = qt2 * 16 + lq;
      *reinterpret_cast<uint2v*>(Pw32 + row * 20 + g * 2) = pw0;
      *reinterpret_cast<uint2v*>(Pw32 + row * 20 + 8 + g * 2) = pw1;
    }
    // ---- PV: out^T += V^T @ P^T for both sub-tiles ----
    short8 pf0 = *reinterpret_cast<const short8*>(Pw + (0 * 16 + lq) * 40 + g * 8);
    short8 pf1 = *reinterpret_cast<const short8*>(Pw + (1 * 16 + lq) * 40 + g * 8);
#pragma unroll
    for (int mt = 0; mt < 4; ++mt) {
      acc[0][mt] = __builtin_amdgcn_mfma_f32_16x16x32_bf16(vf[mt], pf0, acc[0][mt], 0, 0, 0);
      acc[1][mt] = __builtin_amdgcn_mfma_f32_16x16x32_bf16(vf[mt], pf1, acc[1][mt], 0, 0, 0);
    }
  }

  // finalize per-row lsums (reduce per-lane partials over the 4 g-lanes)
#pragma unroll
  for (int qt2 = 0; qt2 < 2; ++qt2) {
    lsum[qt2] += __shfl_xor(lsum[qt2], 16);
    lsum[qt2] += __shfl_xor(lsum[qt2], 32);
  }

  // ---- two-stage merge of the 8 KV splits ----
  __syncthreads();                                 // P dead; safe to overwrite (union)
  if (s >= 4) {                                    // stage A: 4..7 stage
#pragma unroll
    for (int qt2 = 0; qt2 < 2; ++qt2) {
#pragma unroll
      for (int mt = 0; mt < 4; ++mt)
        *reinterpret_cast<floatx4*>(&sm.mg.accS[s - 4][l][qt2 * 16 + mt * 4]) = acc[qt2][mt];
      sm.mg.mS[s - 4][qt2][l] = m[qt2];
      sm.mg.lS[s - 4][qt2][l] = lsum[qt2];
    }
  }
  __syncthreads();
  if (s < 4) {                                     // absorb partner s+4
#pragma unroll
    for (int qt2 = 0; qt2 < 2; ++qt2) {
      float m2 = sm.mg.mS[s][qt2][l], l2 = sm.mg.lS[s][qt2][l];
      float mn = fmaxf(m[qt2], m2);
      float ea = __builtin_amdgcn_exp2f((m[qt2] - mn) * kLog2e);
      float eb = __builtin_amdgcn_exp2f((m2 - mn) * kLog2e);
      lsum[qt2] = lsum[qt2] * ea + l2 * eb;
#pragma unroll
      for (int mt = 0; mt < 4; ++mt) {
        floatx4 a = *reinterpret_cast<const floatx4*>(&sm.mg.accS[s][l][qt2 * 16 + mt * 4]);
#pragma unroll
        for (int r = 0; r < 4; ++r) acc[qt2][mt][r] = acc[qt2][mt][r] * ea + a[r] * eb;
      }
      m[qt2] = mn;
    }
  }
  __syncthreads();
  if (s >= 1 && s < 4) {                           // stage B: 1..3 stage
#pragma unroll
    for (int qt2 = 0; qt2 < 2; ++qt2) {
#pragma unroll
      for (int mt = 0; mt < 4; ++mt)
        *reinterpret_cast<floatx4*>(&sm.mg.accS[s - 1][l][qt2 * 16 + mt * 4]) = acc[qt2][mt];
      sm.mg.mS[s - 1][qt2][l] = m[qt2];
      sm.mg.lS[s - 1][qt2][l] = lsum[qt2];
    }
  }
  __syncthreads();
  if (s == 0) {                                    // wave 0 absorbs 3 + writes out
#pragma unroll
    for (int qt2 = 0; qt2 < 2; ++qt2) {
      float mtot = m[qt2];
#pragma unroll
      for (int si = 0; si < 3; ++si) mtot = fmaxf(mtot, sm.mg.mS[si][qt2][l]);
      float e0 = __builtin_amdgcn_exp2f((m[qt2] - mtot) * kLog2e);
      float ltot = lsum[qt2] * e0;
      float res[4][4];
#pragma unroll
      for (int mt = 0; mt < 4; ++mt)
#pragma unroll
        for (int r = 0; r < 4; ++r) res[mt][r] = acc[qt2][mt][r] * e0;
#pragma unroll
      for (int si = 0; si < 3; ++si) {
        float e = __builtin_amdgcn_exp2f((sm.mg.mS[si][qt2][l] - mtot) * kLog2e);
        ltot += sm.mg.lS[si][qt2][l] * e;
#pragma unroll
        for (int mt = 0; mt < 4; ++mt) {
          floatx4 a = *reinterpret_cast<const floatx4*>(&sm.mg.accS[si][l][qt2 * 16 + mt * 4]);
#pragma unroll
          for (int r = 0; r < 4; ++r) res[mt][r] += a[r] * e;
        }
      }
      float inv = 1.0f / ltot;
      float* obase = out + ((size_t)(b * Tn + q0 + qt2 * 16 + lq)) * Hn;
#pragma unroll
      for (int mt = 0; mt < 4; ++mt) {
        floatx4 o;
#pragma unroll
        for (int r = 0; r < 4; ++r) o[r] = res[mt][r] * inv;
        *reinterpret_cast<floatx4*>(obase + mt * 16 + g * 4) = o;
      }
    }
  }
}

// ---------------------------------------------------------------------------
extern "C" void kernel_launch(void* const* d_in, const int* in_sizes, int n_in,
                              void* d_out, int out_size, void* d_ws, size_t ws_size,
                              hipStream_t stream) {
  const float* x  = (const float*)d_in[0];
  const float* Wq = (const float*)d_in[1];
  const float* bq = (const float*)d_in[2];
  const float* Wk = (const float*)d_in[3];
  const float* bk = (const float*)d_in[4];
  const float* Wv = (const float*)d_in[5];
  const float* bv = (const float*)d_in[6];
  const int* mask = (const int*)d_in[7];
  float* outp = (float*)d_out;

  ushort* wpack = (ushort*)d_ws;                       // 384 KB
  ushort* qbuf  = wpack + 196608;                      // 2 MB bf16 (pre-scaled by 1/8)
  ushort* kbuf  = qbuf + (size_t)16384 * 64;           // 2 MB
  ushort* vT2   = kbuf + (size_t)16384 * 64;           // [8][64][64][32] bf16, 2 MB

  hipLaunchKernelGGL(k_packw, dim3(384), dim3(64), 0, stream, Wq, Wk, Wv, wpack);
  hipLaunchKernelGGL(k_qkv, dim3(1024), dim3(256), 0, stream, x, wpack, bq, bk, bv,
                     qbuf, kbuf, vT2);
  hipLaunchKernelGGL(k_attn, dim3(512), dim3(512), 0, stream, qbuf, kbuf, vT2, mask, outp);
}